// Round 4
// baseline (530.840 us; speedup 1.0000x reference)
//
#include <hip/hip_runtime.h>

#define B_  2
#define S_  512
#define E2_ 512
#define E_  256

#define TT  256   // t-rows per block (stage1)
#define KB  32    // k-tile per step

using f32x4  = __attribute__((ext_vector_type(4))) float;
using bf16x8 = __attribute__((ext_vector_type(8))) short;

__device__ __forceinline__ unsigned short f2bf(float f) {
    unsigned u = __float_as_uint(f);
    unsigned r = (u + 0x7FFFu + ((u >> 16) & 1u)) >> 16;
    return (unsigned short)r;
}
__device__ __forceinline__ float bf2f(unsigned short h) {
    return __uint_as_float(((unsigned)h) << 16);
}
__device__ __forceinline__ float tanh_fast(float x) {
    float e = __expf(2.0f * x);
    return 1.0f - 2.0f / (e + 1.0f);
}

// ---------------- prep: Wd [E2][E] f32 -> WdT hi/lo [E][E2] bf16 ----------------
__global__ void prep_wdt(const float* __restrict__ Wd,
                         unsigned short* __restrict__ WdT_hi,
                         unsigned short* __restrict__ WdT_lo) {
    int idx = blockIdx.x * 256 + threadIdx.x;
    int h = idx >> 8;
    int d = idx & 255;
    float w = Wd[idx];
    unsigned short hi = f2bf(w);
    float lo = w - bf2f(hi);
    WdT_hi[d * E2_ + h] = hi;
    WdT_lo[d * E2_ + h] = f2bf(lo);
}

// ---------------- stage1: logits[b,s,t] -------------------------------------------
// pairs p: 0->(ti=0,sj=0) 1->(0,1) 2->(1,1); diagonal pairs skip waves with t-range > s.
// pair 2 reverses s-mapping so per-CU cost is constant.
__global__ __launch_bounds__(512, 2)
void stage1(const float* __restrict__ q,
            const unsigned short* __restrict__ WdT_hi,
            const unsigned short* __restrict__ WdT_lo,
            const float* __restrict__ vd,
            float* __restrict__ logits /* [B*S, S] */) {
    // swizzled LDS tiles: (row, k) at short-index row*32 + ((k>>3)^((row>>2)&3))*8 + (k&7)
    __shared__ unsigned short sA_hi[TT * KB];   // 16 KiB each
    __shared__ unsigned short sA_lo[TT * KB];
    __shared__ unsigned short sB_hi[E_ * KB];
    __shared__ unsigned short sB_lo[E_ * KB];

    const int x  = blockIdx.x;
    int sl       = x & 255;
    const int p  = x >> 8;
    if (p == 2) sl = 255 - sl;
    const int ti = (p == 2) ? 1 : 0;
    const int sj = (p >= 1) ? 1 : 0;
    const int b  = blockIdx.y;
    const int s  = sj * 256 + sl;
    const int t0 = ti * 256;
    const bool diag = (ti == sj);

    const int tid  = threadIdx.x;
    const int wave = tid >> 6;
    const int lane = tid & 63;
    const int wt   = wave >> 1;   // 0..3 : t-quarter (64 rows)
    const int wd   = wave & 1;    // 0..1 : d-half (128 cols)
    const int l15  = lane & 15;
    const int l4   = lane >> 4;

    // staging mapping: thread -> row (0..255), k-half (0..1); same for A and B tiles
    const int a_row  = tid >> 1;
    const int a_half = tid & 1;
    const int a_sw   = (a_row >> 2) & 3;
    const int a_off0 = a_row * KB + (((2 * a_half)     ^ a_sw) << 3);
    const int a_off1 = a_row * KB + (((2 * a_half + 1) ^ a_sw) << 3);
    const float* qt = q + ((size_t)(b * S_ + t0 + a_row)) * E2_ + a_half * 16;
    const float* qs = q + ((size_t)(b * S_ + s)) * E2_ + a_half * 16;
    const unsigned short* bh = WdT_hi + (size_t)a_row * E2_ + a_half * 16;
    const unsigned short* bl = WdT_lo + (size_t)a_row * E2_ + a_half * 16;

    const bool wactive = (!diag) || (t0 + wt * 64 <= s);

    f32x4 acc[4][8] = {};

    auto STAGE = [&](int k0) {
        // A: C[row][k] = q_t[k]*q_s[k], hi/lo split, 16 elems/thread
        float4 t0v = *(const float4*)(qt + k0);
        float4 t1v = *(const float4*)(qt + k0 + 4);
        float4 t2v = *(const float4*)(qt + k0 + 8);
        float4 t3v = *(const float4*)(qt + k0 + 12);
        float4 s0v = *(const float4*)(qs + k0);
        float4 s1v = *(const float4*)(qs + k0 + 4);
        float4 s2v = *(const float4*)(qs + k0 + 8);
        float4 s3v = *(const float4*)(qs + k0 + 12);
        float pv[16] = {t0v.x, t0v.y, t0v.z, t0v.w, t1v.x, t1v.y, t1v.z, t1v.w,
                        t2v.x, t2v.y, t2v.z, t2v.w, t3v.x, t3v.y, t3v.z, t3v.w};
        float sv[16] = {s0v.x, s0v.y, s0v.z, s0v.w, s1v.x, s1v.y, s1v.z, s1v.w,
                        s2v.x, s2v.y, s2v.z, s2v.w, s3v.x, s3v.y, s3v.z, s3v.w};
        bf16x8 h0, l0, h1, l1;
#pragma unroll
        for (int j = 0; j < 8; ++j) {
            float pr = pv[j] * sv[j];
            unsigned short hi = f2bf(pr);
            h0[j] = (short)hi;
            l0[j] = (short)f2bf(pr - bf2f(hi));
        }
#pragma unroll
        for (int j = 0; j < 8; ++j) {
            float pr = pv[8 + j] * sv[8 + j];
            unsigned short hi = f2bf(pr);
            h1[j] = (short)hi;
            l1[j] = (short)f2bf(pr - bf2f(hi));
        }
        *(bf16x8*)&sA_hi[a_off0] = h0;
        *(bf16x8*)&sA_hi[a_off1] = h1;
        *(bf16x8*)&sA_lo[a_off0] = l0;
        *(bf16x8*)&sA_lo[a_off1] = l1;
        // B: copy WdT hi/lo rows
        *(int4*)&sB_hi[a_off0] = *(const int4*)(bh + k0);
        *(int4*)&sB_hi[a_off1] = *(const int4*)(bh + k0 + 8);
        *(int4*)&sB_lo[a_off0] = *(const int4*)(bl + k0);
        *(int4*)&sB_lo[a_off1] = *(const int4*)(bl + k0 + 8);
    };

    STAGE(0);
    __syncthreads();

    for (int ko = 0; ko < E2_ / KB; ++ko) {
        bf16x8 afh[4], afl[4], bfh[8], bfl[8];
        if (wactive) {
#pragma unroll
            for (int ft = 0; ft < 4; ++ft) {
                int row = wt * 64 + ft * 16 + l15;
                int off = row * KB + ((l4 ^ ((row >> 2) & 3)) << 3);
                afh[ft] = *(const bf16x8*)&sA_hi[off];
                afl[ft] = *(const bf16x8*)&sA_lo[off];
            }
#pragma unroll
            for (int fd = 0; fd < 8; ++fd) {
                int d   = wd * 128 + fd * 16 + l15;
                int off = d * KB + ((l4 ^ ((d >> 2) & 3)) << 3);
                bfh[fd] = *(const bf16x8*)&sB_hi[off];
                bfl[fd] = *(const bf16x8*)&sB_lo[off];
            }
        }
        __syncthreads();   // reads done -> safe to overwrite tiles
        if (ko < E2_ / KB - 1) STAGE((ko + 1) * KB);   // overlapped with MFMA below
        if (wactive) {
            __builtin_amdgcn_s_setprio(1);
#pragma unroll
            for (int ft = 0; ft < 4; ++ft) {
#pragma unroll
                for (int fd = 0; fd < 8; ++fd) {
                    acc[ft][fd] = __builtin_amdgcn_mfma_f32_16x16x32_bf16(afh[ft], bfh[fd], acc[ft][fd], 0, 0, 0);
                    acc[ft][fd] = __builtin_amdgcn_mfma_f32_16x16x32_bf16(afh[ft], bfl[fd], acc[ft][fd], 0, 0, 0);
                    acc[ft][fd] = __builtin_amdgcn_mfma_f32_16x16x32_bf16(afl[ft], bfh[fd], acc[ft][fd], 0, 0, 0);
                }
            }
            __builtin_amdgcn_s_setprio(0);
        }
        __syncthreads();   // staging done before next iteration's reads
    }

    // ---- epilogue: tanh, *vd, reduce over d
    float* sRed = (float*)sA_hi;   // 256*2 floats, overlay
    if (wactive) {
        float vdr[8];
#pragma unroll
        for (int fd = 0; fd < 8; ++fd) vdr[fd] = vd[wd * 128 + fd * 16 + l15];
#pragma unroll
        for (int ft = 0; ft < 4; ++ft) {
#pragma unroll
            for (int r = 0; r < 4; ++r) {
                float pp = 0.f;
#pragma unroll
                for (int fd = 0; fd < 8; ++fd)
                    pp += tanh_fast(acc[ft][fd][r]) * vdr[fd];
                pp += __shfl_xor(pp, 1);
                pp += __shfl_xor(pp, 2);
                pp += __shfl_xor(pp, 4);
                pp += __shfl_xor(pp, 8);
                if (l15 == 0) {
                    int rl = wt * 64 + ft * 16 + l4 * 4 + r;
                    sRed[rl * 2 + wd] = pp;
                }
            }
        }
    }
    __syncthreads();
    if (tid < TT) {
        int t = t0 + tid;
        if (!diag || t <= s) {
            float v = sRed[tid * 2 + 0] + sRed[tid * 2 + 1];
            logits[((size_t)(b * S_ + s)) * S_ + t] = v;   // direct
            logits[((size_t)(b * S_ + t)) * S_ + s] = v;   // mirror (bitwise-identical)
        }
    }
}

// ---------------- softmax in place over rows of 512 ------------------------------
__global__ void softmax_k(float* __restrict__ atten) {
    const int row  = blockIdx.x;
    const int lane = threadIdx.x;
    float* p = atten + (size_t)row * S_;
    float4 v0 = *(float4*)(p + lane * 8);
    float4 v1 = *(float4*)(p + lane * 8 + 4);
    float vv[8] = {v0.x, v0.y, v0.z, v0.w, v1.x, v1.y, v1.z, v1.w};
    float m = vv[0];
#pragma unroll
    for (int j = 1; j < 8; ++j) m = fmaxf(m, vv[j]);
#pragma unroll
    for (int off = 1; off < 64; off <<= 1) m = fmaxf(m, __shfl_xor(m, off));
    float ssum = 0.f;
#pragma unroll
    for (int j = 0; j < 8; ++j) { vv[j] = __expf(vv[j] - m); ssum += vv[j]; }
#pragma unroll
    for (int off = 1; off < 64; off <<= 1) ssum += __shfl_xor(ssum, off);
    float inv = 1.0f / ssum;
    float4 o0 = {vv[0] * inv, vv[1] * inv, vv[2] * inv, vv[3] * inv};
    float4 o1 = {vv[4] * inv, vv[5] * inv, vv[6] * inv, vv[7] * inv};
    *(float4*)(p + lane * 8)     = o0;
    *(float4*)(p + lane * 8 + 4) = o1;
}

// ---------------- context = atten @ value (f32 tiled) -----------------------------
__global__ __launch_bounds__(256)
void context_k(const float* __restrict__ atten, const float* __restrict__ value,
               float* __restrict__ ctx) {
    __shared__ float sA[32][65];
    __shared__ float sV[64][65];
    const int b  = blockIdx.z;
    const int s0 = blockIdx.y * 32;
    const int e0 = blockIdx.x * 64;
    const int tid = threadIdx.x;
    const int ts = tid >> 4;
    const int te = tid & 15;

    float acc[2][4] = {};
    for (int k0 = 0; k0 < S_; k0 += 64) {
        {
            int r = tid >> 3;
            int c = (tid & 7) * 8;
            const float* ga = atten + ((size_t)(b * S_ + s0 + r)) * S_ + k0 + c;
            *(float4*)&sA[r][c]     = *(const float4*)ga;
            *(float4*)&sA[r][c + 4] = *(const float4*)(ga + 4);
        }
        {
            int r = tid >> 2;
            int c = (tid & 3) * 16;
            const float* gv = value + ((size_t)(b * S_ + k0 + r)) * E2_ + e0 + c;
#pragma unroll
            for (int j = 0; j < 16; j += 4)
                *(float4*)&sV[r][c + j] = *(const float4*)(gv + j);
        }
        __syncthreads();
#pragma unroll 8
        for (int kk = 0; kk < 64; ++kk) {
            float a0 = sA[ts * 2 + 0][kk];
            float a1 = sA[ts * 2 + 1][kk];
#pragma unroll
            for (int j = 0; j < 4; ++j) {
                float vvv = sV[kk][te * 4 + j];
                acc[0][j] += a0 * vvv;
                acc[1][j] += a1 * vvv;
            }
        }
        __syncthreads();
    }
#pragma unroll
    for (int i = 0; i < 2; ++i)
#pragma unroll
        for (int j = 0; j < 4; ++j)
            ctx[((size_t)(b * S_ + s0 + ts * 2 + i)) * E2_ + e0 + te * 4 + j] = acc[i][j];
}

extern "C" void kernel_launch(void* const* d_in, const int* in_sizes, int n_in,
                              void* d_out, int out_size, void* d_ws, size_t ws_size,
                              hipStream_t stream) {
    const float* query = (const float*)d_in[0];
    const float* value = (const float*)d_in[1];
    const float* Wd    = (const float*)d_in[2];
    const float* vd    = (const float*)d_in[3];

    float* out   = (float*)d_out;
    float* ctx   = out;                          // [B,S,E2]
    float* atten = out + (size_t)B_ * S_ * E2_;  // [B,S,S]

    const size_t wdt_bytes = (size_t)2 * E_ * E2_ * sizeof(unsigned short);
    unsigned short* wdt_hi;
    if (ws_size >= wdt_bytes) {
        wdt_hi = (unsigned short*)d_ws;
    } else {
        wdt_hi = (unsigned short*)ctx;   // overwritten later by context_k
    }
    unsigned short* wdt_lo = wdt_hi + (size_t)E_ * E2_;

    prep_wdt<<<dim3(512), dim3(256), 0, stream>>>(Wd, wdt_hi, wdt_lo);
    // 3 tile-pairs * 256 s-values = 768 blocks per batch
    stage1<<<dim3(768, B_), dim3(512), 0, stream>>>(query, wdt_hi, wdt_lo, vd, atten);
    softmax_k<<<dim3(B_ * S_), dim3(64), 0, stream>>>(atten);
    context_k<<<dim3(E2_ / 64, S_ / 32, B_), dim3(256), 0, stream>>>(atten, value, ctx);
}

// Round 5
// 247.004 us; speedup vs baseline: 2.1491x; 2.1491x over previous
//
#include <hip/hip_runtime.h>

#define B_  2
#define S_  512
#define E2_ 512
#define E_  256

#define TT  128   // t-tile per block (stage1)
#define KB  32    // k-tile per step

using f32x4 = __attribute__((ext_vector_type(4))) float;
using f16x8 = __attribute__((ext_vector_type(8))) _Float16;

__device__ __forceinline__ float tanh_fast(float x) {
    // NaN-safe: e->inf gives 1-0=1 ; e->0 gives 1-2=-1
    float e = __expf(2.0f * x);
    return 1.0f - 2.0f / (e + 1.0f);
}

// ---------------- prep: Wd [E2][E] f32 -> WdT f16 [E][E2] -----------------------
__global__ void prep_wdt(const float* __restrict__ Wd, _Float16* __restrict__ WdT) {
    int idx = blockIdx.x * 256 + threadIdx.x;   // 0 .. 131071
    int h = idx >> 8;      // 0..511
    int d = idx & 255;     // 0..255
    WdT[d * E2_ + h] = (_Float16)Wd[idx];       // RN convert
}

// ---------------- stage1: logits[b,s,t], dense triangular grid -------------------
// blockIdx.x in [0,1280): p = x>>7 tile-pair (ti<=sj), sl = x&127 selects s
__global__ __launch_bounds__(512)
void stage1(const float* __restrict__ q,
            const _Float16* __restrict__ WdT,
            const float* __restrict__ vd,
            float* __restrict__ logits /* [B*S, S] */) {
    const int p  = blockIdx.x >> 7;
    const int sl = blockIdx.x & 127;
    const int b  = blockIdx.y;
    const int sj = (p >= 6) ? 3 : (p >= 3) ? 2 : (p >= 1) ? 1 : 0;
    const int ti = p - ((sj * (sj + 1)) >> 1);
    const int s  = sj * TT + sl;
    const int t0 = ti * TT;

    // swizzled LDS tiles: (row, k) at elem-index row*32 + ((k>>3)^((row>>2)&3))*8 + (k&7)
    __shared__ _Float16 sA[TT * KB];   // 8 KiB
    __shared__ _Float16 sB[E_ * KB];   // 16 KiB
    __shared__ float sQs[E2_];         // 2 KiB
    __shared__ float sVd[E_];          // 1 KiB

    const int tid = threadIdx.x;
    sQs[tid] = q[((size_t)(b * S_ + s)) * E2_ + tid];
    if (tid < E_) sVd[tid] = vd[tid];
    __syncthreads();

    const int wave = tid >> 6;
    const int lane = tid & 63;
    const int wt   = wave >> 2;   // 0..1 : t-half (64 rows)
    const int wd   = wave & 3;    // 0..3 : d-quarter (64 cols)
    const int l15  = lane & 15;
    const int l4   = lane >> 4;   // 0..3

    // staging mappings (hoisted)
    const int a_row = tid >> 2;         // 0..127
    const int a_g   = tid & 3;          // k-granule
    const int a_off = a_row * KB + ((a_g ^ ((a_row >> 2) & 3)) << 3);
    const float* qt = q + ((size_t)(b * S_ + t0 + a_row)) * E2_ + a_g * 8;

    const int b_row  = tid >> 1;        // 0..255
    const int b_half = tid & 1;
    const int b_sw   = (b_row >> 2) & 3;
    const int b_off0 = b_row * KB + (((2 * b_half)     ^ b_sw) << 3);
    const int b_off1 = b_row * KB + (((2 * b_half + 1) ^ b_sw) << 3);
    const _Float16* bw = WdT + (size_t)b_row * E2_ + b_half * 16;

    auto STAGE = [&](int k0) {
        // A: C[row][k] = q_t[k] * q_s[k] -> f16 (RN), one b128 write
        float4 t0v = *(const float4*)(qt + k0);
        float4 t1v = *(const float4*)(qt + k0 + 4);
        float4 q0v = *(const float4*)&sQs[k0 + a_g * 8];
        float4 q1v = *(const float4*)&sQs[k0 + a_g * 8 + 4];
        f16x8 hv;
        hv[0] = (_Float16)(t0v.x * q0v.x);
        hv[1] = (_Float16)(t0v.y * q0v.y);
        hv[2] = (_Float16)(t0v.z * q0v.z);
        hv[3] = (_Float16)(t0v.w * q0v.w);
        hv[4] = (_Float16)(t1v.x * q1v.x);
        hv[5] = (_Float16)(t1v.y * q1v.y);
        hv[6] = (_Float16)(t1v.z * q1v.z);
        hv[7] = (_Float16)(t1v.w * q1v.w);
        *(f16x8*)&sA[a_off] = hv;
        // B: copy WdT row slice (16 f16 = 2 b128)
        *(int4*)&sB[b_off0] = *(const int4*)(bw + k0);
        *(int4*)&sB[b_off1] = *(const int4*)(bw + k0 + 8);
    };

    f32x4 acc[4][4] = {};

    STAGE(0);
    __syncthreads();

    for (int ko = 0; ko < E2_ / KB; ++ko) {
        f16x8 af[4], bf[4];
#pragma unroll
        for (int ft = 0; ft < 4; ++ft) {
            int row = wt * 64 + ft * 16 + l15;
            int off = row * KB + ((l4 ^ ((row >> 2) & 3)) << 3);
            af[ft] = *(const f16x8*)&sA[off];
        }
#pragma unroll
        for (int fd = 0; fd < 4; ++fd) {
            int drow = wd * 64 + fd * 16 + l15;
            int off  = drow * KB + ((l4 ^ ((drow >> 2) & 3)) << 3);
            bf[fd] = *(const f16x8*)&sB[off];
        }
        __syncthreads();                       // reads done -> tiles reusable
        if (ko < E2_ / KB - 1) STAGE((ko + 1) * KB);   // overlap with MFMA
        __builtin_amdgcn_s_setprio(1);
#pragma unroll
        for (int ft = 0; ft < 4; ++ft) {
#pragma unroll
            for (int fd = 0; fd < 4; ++fd) {
                acc[ft][fd] = __builtin_amdgcn_mfma_f32_16x16x32_f16(af[ft], bf[fd], acc[ft][fd], 0, 0, 0);
            }
        }
        __builtin_amdgcn_s_setprio(0);
        __syncthreads();                       // staging done before next reads
    }

    // ---- epilogue: tanh, *vd, reduce over d  (sRed overlays sA, safe after barrier)
    float* sRed = (float*)sA;
#pragma unroll
    for (int ft = 0; ft < 4; ++ft) {
#pragma unroll
        for (int r = 0; r < 4; ++r) {
            float pp = 0.f;
#pragma unroll
            for (int fd = 0; fd < 4; ++fd) {
                int d = wd * 64 + fd * 16 + l15;
                pp += tanh_fast(acc[ft][fd][r]) * sVd[d];
            }
            pp += __shfl_xor(pp, 1);
            pp += __shfl_xor(pp, 2);
            pp += __shfl_xor(pp, 4);
            pp += __shfl_xor(pp, 8);
            if (l15 == 0) {
                int tl = wt * 64 + ft * 16 + l4 * 4 + r;
                sRed[tl * 4 + wd] = pp;
            }
        }
    }
    __syncthreads();
    if (tid < TT) {
        float v = sRed[tid * 4 + 0] + sRed[tid * 4 + 1] + sRed[tid * 4 + 2] + sRed[tid * 4 + 3];
        int t = t0 + tid;
        logits[((size_t)(b * S_ + s)) * S_ + t] = v;   // direct
        logits[((size_t)(b * S_ + t)) * S_ + s] = v;   // mirror (bitwise-identical)
    }
}

// ---------------- softmax in place over rows of 512 ------------------------------
__global__ void softmax_k(float* __restrict__ atten) {
    const int row  = blockIdx.x;
    const int lane = threadIdx.x;
    float* p = atten + (size_t)row * S_;
    float4 v0 = *(float4*)(p + lane * 8);
    float4 v1 = *(float4*)(p + lane * 8 + 4);
    float vv[8] = {v0.x, v0.y, v0.z, v0.w, v1.x, v1.y, v1.z, v1.w};
    float m = vv[0];
#pragma unroll
    for (int j = 1; j < 8; ++j) m = fmaxf(m, vv[j]);
#pragma unroll
    for (int off = 1; off < 64; off <<= 1) m = fmaxf(m, __shfl_xor(m, off));
    float ssum = 0.f;
#pragma unroll
    for (int j = 0; j < 8; ++j) { vv[j] = __expf(vv[j] - m); ssum += vv[j]; }
#pragma unroll
    for (int off = 1; off < 64; off <<= 1) ssum += __shfl_xor(ssum, off);
    float inv = 1.0f / ssum;
    float4 o0 = {vv[0] * inv, vv[1] * inv, vv[2] * inv, vv[3] * inv};
    float4 o1 = {vv[4] * inv, vv[5] * inv, vv[6] * inv, vv[7] * inv};
    *(float4*)(p + lane * 8)     = o0;
    *(float4*)(p + lane * 8 + 4) = o1;
}

// ---------------- context = atten @ value (f32 tiled) -----------------------------
__global__ __launch_bounds__(256)
void context_k(const float* __restrict__ atten, const float* __restrict__ value,
               float* __restrict__ ctx) {
    __shared__ float sA[32][65];
    __shared__ float sV[64][65];
    const int b  = blockIdx.z;
    const int s0 = blockIdx.y * 32;
    const int e0 = blockIdx.x * 64;
    const int tid = threadIdx.x;
    const int ts = tid >> 4;
    const int te = tid & 15;

    float acc[2][4] = {};
    for (int k0 = 0; k0 < S_; k0 += 64) {
        {
            int r = tid >> 3;
            int c = (tid & 7) * 8;
            const float* ga = atten + ((size_t)(b * S_ + s0 + r)) * S_ + k0 + c;
            *(float4*)&sA[r][c]     = *(const float4*)ga;
            *(float4*)&sA[r][c + 4] = *(const float4*)(ga + 4);
        }
        {
            int r = tid >> 2;
            int c = (tid & 3) * 16;
            const float* gv = value + ((size_t)(b * S_ + k0 + r)) * E2_ + e0 + c;
#pragma unroll
            for (int j = 0; j < 16; j += 4)
                *(float4*)&sV[r][c + j] = *(const float4*)(gv + j);
        }
        __syncthreads();
#pragma unroll 8
        for (int kk = 0; kk < 64; ++kk) {
            float a0 = sA[ts * 2 + 0][kk];
            float a1 = sA[ts * 2 + 1][kk];
#pragma unroll
            for (int j = 0; j < 4; ++j) {
                float vvv = sV[kk][te * 4 + j];
                acc[0][j] += a0 * vvv;
                acc[1][j] += a1 * vvv;
            }
        }
        __syncthreads();
    }
#pragma unroll
    for (int i = 0; i < 2; ++i)
#pragma unroll
        for (int j = 0; j < 4; ++j)
            ctx[((size_t)(b * S_ + s0 + ts * 2 + i)) * E2_ + e0 + te * 4 + j] = acc[i][j];
}

extern "C" void kernel_launch(void* const* d_in, const int* in_sizes, int n_in,
                              void* d_out, int out_size, void* d_ws, size_t ws_size,
                              hipStream_t stream) {
    const float* query = (const float*)d_in[0];
    const float* value = (const float*)d_in[1];
    const float* Wd    = (const float*)d_in[2];
    const float* vd    = (const float*)d_in[3];

    float* out   = (float*)d_out;
    float* ctx   = out;                          // [B,S,E2]
    float* atten = out + (size_t)B_ * S_ * E2_;  // [B,S,S]

    // WdT f16: 256*512*2B = 256 KiB
    const size_t wdt_bytes = (size_t)E_ * E2_ * sizeof(_Float16);
    _Float16* wdt;
    if (ws_size >= wdt_bytes) {
        wdt = (_Float16*)d_ws;
    } else {
        wdt = (_Float16*)ctx;   // overwritten later by context_k
    }

    prep_wdt<<<dim3(512), dim3(256), 0, stream>>>(Wd, wdt);
    // dense triangular grid: 10 tile-pairs * 128 s-values = 1280 blocks per batch
    stage1<<<dim3(1280, B_), dim3(512), 0, stream>>>(query, wdt, vd, atten);
    softmax_k<<<dim3(B_ * S_), dim3(64), 0, stream>>>(atten);
    context_k<<<dim3(E2_ / 64, S_ / 32, B_), dim3(256), 0, stream>>>(atten, value, ctx);
}

// Round 6
// 214.866 us; speedup vs baseline: 2.4706x; 1.1496x over previous
//
#include <hip/hip_runtime.h>

#define B_  2
#define S_  512
#define E2_ 512
#define E_  256

#define TT  128   // t-tile per block (stage1)
#define KB  32    // k-tile per step
#define LDK 40    // padded LDS row stride in f16 elems (80 B, 16B-aligned, bank-clean)

using f32x4 = __attribute__((ext_vector_type(4))) float;
using f16x8 = __attribute__((ext_vector_type(8))) _Float16;

__device__ __forceinline__ float tanh_fast(float x) {
    // NaN-safe: e->inf gives 1-0=1 ; e->0 gives 1-2=-1
    float e = __expf(2.0f * x);
    return 1.0f - 2.0f / (e + 1.0f);
}

// ---------------- prep: Wd [E2][E] f32 -> WdT f16 [E][E2] -----------------------
__global__ void prep_wdt(const float* __restrict__ Wd, _Float16* __restrict__ WdT) {
    int idx = blockIdx.x * 256 + threadIdx.x;   // 0 .. 131071
    int h = idx >> 8;      // 0..511
    int d = idx & 255;     // 0..255
    WdT[d * E2_ + h] = (_Float16)Wd[idx];       // RN convert
}

// ---------------- stage1: logits[b,s,t], dense triangular grid -------------------
// blockIdx.x in [0,1280): p = x>>7 tile-pair (ti<=sj), sl = x&127 selects s
__global__ __launch_bounds__(512)
void stage1(const float* __restrict__ q,
            const _Float16* __restrict__ WdT,
            const float* __restrict__ vd,
            float* __restrict__ logits /* [B*S, S] */) {
    const int p  = blockIdx.x >> 7;
    const int sl = blockIdx.x & 127;
    const int b  = blockIdx.y;
    const int sj = (p >= 6) ? 3 : (p >= 3) ? 2 : (p >= 1) ? 1 : 0;
    const int ti = p - ((sj * (sj + 1)) >> 1);
    const int s  = sj * TT + sl;
    const int t0 = ti * TT;

    __shared__ _Float16 sA[TT * LDK];   // 10 KiB
    __shared__ _Float16 sB[E_ * LDK];   // 20 KiB
    __shared__ float sQs[E2_];          // 2 KiB
    __shared__ float sVd[E_];           // 1 KiB

    const int tid = threadIdx.x;
    sQs[tid] = q[((size_t)(b * S_ + s)) * E2_ + tid];
    if (tid < E_) sVd[tid] = vd[tid];
    __syncthreads();

    const int wave = tid >> 6;
    const int lane = tid & 63;
    const int wt   = wave >> 2;   // 0..1 : t-half (64 rows)
    const int wd   = wave & 3;    // 0..3 : d-quarter (64 cols)
    const int l15  = lane & 15;
    const int l4   = lane >> 4;   // 0..3

    // staging mappings (hoisted)
    const int a_row = tid >> 2;         // 0..127
    const int a_g   = tid & 3;          // k-granule
    const int a_off = a_row * LDK + a_g * 8;
    const float* qt = q + ((size_t)(b * S_ + t0 + a_row)) * E2_ + a_g * 8;

    const int b_row  = tid >> 1;        // 0..255
    const int b_half = tid & 1;
    const int b_off0 = b_row * LDK + b_half * 16;
    const int b_off1 = b_off0 + 8;
    const _Float16* bw = WdT + (size_t)b_row * E2_ + b_half * 16;

    // prefetch registers (global -> reg, written to LDS one step later)
    float4 r_t0, r_t1;
    int4   r_b0, r_b1;

    auto LOAD = [&](int k0) {
        r_t0 = *(const float4*)(qt + k0);
        r_t1 = *(const float4*)(qt + k0 + 4);
        r_b0 = *(const int4*)(bw + k0);
        r_b1 = *(const int4*)(bw + k0 + 8);
    };
    auto WRITE = [&](int k0) {
        float4 q0v = *(const float4*)&sQs[k0 + a_g * 8];
        float4 q1v = *(const float4*)&sQs[k0 + a_g * 8 + 4];
        f16x8 hv;
        hv[0] = (_Float16)(r_t0.x * q0v.x);
        hv[1] = (_Float16)(r_t0.y * q0v.y);
        hv[2] = (_Float16)(r_t0.z * q0v.z);
        hv[3] = (_Float16)(r_t0.w * q0v.w);
        hv[4] = (_Float16)(r_t1.x * q1v.x);
        hv[5] = (_Float16)(r_t1.y * q1v.y);
        hv[6] = (_Float16)(r_t1.z * q1v.z);
        hv[7] = (_Float16)(r_t1.w * q1v.w);
        *(f16x8*)&sA[a_off] = hv;
        *(int4*)&sB[b_off0] = r_b0;
        *(int4*)&sB[b_off1] = r_b1;
    };

    f32x4 acc[4][4] = {};

    LOAD(0);
    WRITE(0);
    __syncthreads();

    for (int ko = 0; ko < E2_ / KB; ++ko) {
        if (ko < E2_ / KB - 1) LOAD((ko + 1) * KB);   // global latency hides below
        f16x8 af[4], bf[4];
#pragma unroll
        for (int ft = 0; ft < 4; ++ft) {
            int row = wt * 64 + ft * 16 + l15;
            af[ft] = *(const f16x8*)&sA[row * LDK + l4 * 8];
        }
#pragma unroll
        for (int fd = 0; fd < 4; ++fd) {
            int drow = wd * 64 + fd * 16 + l15;
            bf[fd] = *(const f16x8*)&sB[drow * LDK + l4 * 8];
        }
        __syncthreads();                        // frag reads done -> tiles reusable
        if (ko < E2_ / KB - 1) WRITE((ko + 1) * KB);   // reg->LDS; drains under MFMA
        __builtin_amdgcn_s_setprio(1);
#pragma unroll
        for (int ft = 0; ft < 4; ++ft) {
#pragma unroll
            for (int fd = 0; fd < 4; ++fd) {
                acc[ft][fd] = __builtin_amdgcn_mfma_f32_16x16x32_f16(af[ft], bf[fd], acc[ft][fd], 0, 0, 0);
            }
        }
        __builtin_amdgcn_s_setprio(0);
        __syncthreads();                        // staged tile visible for next reads
    }

    // ---- epilogue: tanh, *vd, reduce over d  (sRed overlays sA, safe after barrier)
    float* sRed = (float*)sA;
#pragma unroll
    for (int ft = 0; ft < 4; ++ft) {
#pragma unroll
        for (int r = 0; r < 4; ++r) {
            float pp = 0.f;
#pragma unroll
            for (int fd = 0; fd < 4; ++fd) {
                int d = wd * 64 + fd * 16 + l15;
                pp += tanh_fast(acc[ft][fd][r]) * sVd[d];
            }
            pp += __shfl_xor(pp, 1);
            pp += __shfl_xor(pp, 2);
            pp += __shfl_xor(pp, 4);
            pp += __shfl_xor(pp, 8);
            if (l15 == 0) {
                int tl = wt * 64 + ft * 16 + l4 * 4 + r;
                sRed[tl * 4 + wd] = pp;
            }
        }
    }
    __syncthreads();
    if (tid < TT) {
        float v = sRed[tid * 4 + 0] + sRed[tid * 4 + 1] + sRed[tid * 4 + 2] + sRed[tid * 4 + 3];
        int t = t0 + tid;
        logits[((size_t)(b * S_ + s)) * S_ + t] = v;   // direct
        logits[((size_t)(b * S_ + t)) * S_ + s] = v;   // mirror (bitwise-identical)
    }
}

// ---------------- softmax in place over rows of 512 ------------------------------
__global__ void softmax_k(float* __restrict__ atten) {
    const int row  = blockIdx.x;
    const int lane = threadIdx.x;
    float* p = atten + (size_t)row * S_;
    float4 v0 = *(float4*)(p + lane * 8);
    float4 v1 = *(float4*)(p + lane * 8 + 4);
    float vv[8] = {v0.x, v0.y, v0.z, v0.w, v1.x, v1.y, v1.z, v1.w};
    float m = vv[0];
#pragma unroll
    for (int j = 1; j < 8; ++j) m = fmaxf(m, vv[j]);
#pragma unroll
    for (int off = 1; off < 64; off <<= 1) m = fmaxf(m, __shfl_xor(m, off));
    float ssum = 0.f;
#pragma unroll
    for (int j = 0; j < 8; ++j) { vv[j] = __expf(vv[j] - m); ssum += vv[j]; }
#pragma unroll
    for (int off = 1; off < 64; off <<= 1) ssum += __shfl_xor(ssum, off);
    float inv = 1.0f / ssum;
    float4 o0 = {vv[0] * inv, vv[1] * inv, vv[2] * inv, vv[3] * inv};
    float4 o1 = {vv[4] * inv, vv[5] * inv, vv[6] * inv, vv[7] * inv};
    *(float4*)(p + lane * 8)     = o0;
    *(float4*)(p + lane * 8 + 4) = o1;
}

// ---------------- context = atten @ value (f32 tiled) -----------------------------
__global__ __launch_bounds__(256)
void context_k(const float* __restrict__ atten, const float* __restrict__ value,
               float* __restrict__ ctx) {
    __shared__ float sA[32][65];
    __shared__ float sV[64][65];
    const int b  = blockIdx.z;
    const int s0 = blockIdx.y * 32;
    const int e0 = blockIdx.x * 64;
    const int tid = threadIdx.x;
    const int ts = tid >> 4;
    const int te = tid & 15;

    float acc[2][4] = {};
    for (int k0 = 0; k0 < S_; k0 += 64) {
        {
            int r = tid >> 3;
            int c = (tid & 7) * 8;
            const float* ga = atten + ((size_t)(b * S_ + s0 + r)) * S_ + k0 + c;
            *(float4*)&sA[r][c]     = *(const float4*)ga;
            *(float4*)&sA[r][c + 4] = *(const float4*)(ga + 4);
        }
        {
            int r = tid >> 2;
            int c = (tid & 3) * 16;
            const float* gv = value + ((size_t)(b * S_ + k0 + r)) * E2_ + e0 + c;
#pragma unroll
            for (int j = 0; j < 16; j += 4)
                *(float4*)&sV[r][c + j] = *(const float4*)(gv + j);
        }
        __syncthreads();
#pragma unroll 8
        for (int kk = 0; kk < 64; ++kk) {
            float a0 = sA[ts * 2 + 0][kk];
            float a1 = sA[ts * 2 + 1][kk];
#pragma unroll
            for (int j = 0; j < 4; ++j) {
                float vvv = sV[kk][te * 4 + j];
                acc[0][j] += a0 * vvv;
                acc[1][j] += a1 * vvv;
            }
        }
        __syncthreads();
    }
#pragma unroll
    for (int i = 0; i < 2; ++i)
#pragma unroll
        for (int j = 0; j < 4; ++j)
            ctx[((size_t)(b * S_ + s0 + ts * 2 + i)) * E2_ + e0 + te * 4 + j] = acc[i][j];
}

extern "C" void kernel_launch(void* const* d_in, const int* in_sizes, int n_in,
                              void* d_out, int out_size, void* d_ws, size_t ws_size,
                              hipStream_t stream) {
    const float* query = (const float*)d_in[0];
    const float* value = (const float*)d_in[1];
    const float* Wd    = (const float*)d_in[2];
    const float* vd    = (const float*)d_in[3];

    float* out   = (float*)d_out;
    float* ctx   = out;                          // [B,S,E2]
    float* atten = out + (size_t)B_ * S_ * E2_;  // [B,S,S]

    // WdT f16: 256*512*2B = 256 KiB
    const size_t wdt_bytes = (size_t)E_ * E2_ * sizeof(_Float16);
    _Float16* wdt;
    if (ws_size >= wdt_bytes) {
        wdt = (_Float16*)d_ws;
    } else {
        wdt = (_Float16*)ctx;   // overwritten later by context_k
    }

    prep_wdt<<<dim3(512), dim3(256), 0, stream>>>(Wd, wdt);
    // dense triangular grid: 10 tile-pairs * 128 s-values = 1280 blocks per batch
    stage1<<<dim3(1280, B_), dim3(512), 0, stream>>>(query, wdt, vd, atten);
    softmax_k<<<dim3(B_ * S_), dim3(64), 0, stream>>>(atten);
    context_k<<<dim3(E2_ / 64, S_ / 32, B_), dim3(256), 0, stream>>>(atten, value, ctx);
}

// Round 8
// 180.535 us; speedup vs baseline: 2.9404x; 1.1902x over previous
//
#include <hip/hip_runtime.h>

#define B_  2
#define S_  512
#define E2_ 512
#define E_  256

#define TT  128   // t-tile per block (stage1)
#define KB  32    // k-tile per step
#define LDK 40    // padded LDS row stride (f16 elems); pads never read

using f32x4 = __attribute__((ext_vector_type(4))) float;
using f16x8 = __attribute__((ext_vector_type(8))) _Float16;

__device__ __forceinline__ float tanh_fast(float x) {
    // NaN-safe: e->inf gives 1-0=1 ; e->0 gives 1-2=-1
    float e = __expf(2.0f * x);
    return 1.0f - 2.0f / (e + 1.0f);
}

__device__ __forceinline__ void gld16(const void* g, void* l) {
    __builtin_amdgcn_global_load_lds(
        (const __attribute__((address_space(1))) unsigned int*)g,
        (__attribute__((address_space(3))) unsigned int*)l, 16, 0, 0);
}

#define SBAR() __builtin_amdgcn_sched_barrier(0)

// ---- prep: Wd [E2][E] f32 -> Wp[ko][d][LDK] f16 step-tile images (padded) ------
__global__ void prep_wdt(const float* __restrict__ Wd, _Float16* __restrict__ Wp) {
    int idx = blockIdx.x * 256 + threadIdx.x;   // 0 .. 131071
    int h = idx >> 8;      // 0..511  (k index)
    int d = idx & 255;     // 0..255
    int ko = h >> 5;       // step
    int kk = h & 31;       // col within step
    Wp[(size_t)ko * (E_ * LDK) + d * LDK + kk] = (_Float16)Wd[idx];
}

// ---------------- stage1: logits[b,s,t], dense triangular grid -------------------
// blockIdx.x in [0,1280): p = x>>7 tile-pair (ti<=sj), sl = x&127 selects s
__global__ __launch_bounds__(256, 2)
void stage1(const float* __restrict__ q,
            const _Float16* __restrict__ Wp,
            const float* __restrict__ vd,
            float* __restrict__ logits /* [B*S, S] */) {
    const int p  = blockIdx.x >> 7;
    const int sl = blockIdx.x & 127;
    const int b  = blockIdx.y;
    const int sj = (p >= 6) ? 3 : (p >= 3) ? 2 : (p >= 1) ? 1 : 0;
    const int ti = p - ((sj * (sj + 1)) >> 1);
    const int s  = sj * TT + sl;
    const int t0 = ti * TT;

    __shared__ _Float16 sA[2][TT * LDK];   // 2 x 10 KiB
    __shared__ _Float16 sB[2][E_ * LDK];   // 2 x 20 KiB
    __shared__ float sQs[E2_];             // 2 KiB
    __shared__ float sVd[E_];              // 1 KiB

    const int tid = threadIdx.x;   // 0..255
    {
        const float* qsrow = q + ((size_t)(b * S_ + s)) * E2_;
        sQs[tid]       = qsrow[tid];
        sQs[tid + 256] = qsrow[tid + 256];
        if (tid < E_) sVd[tid] = vd[tid];
    }
    __syncthreads();

    const int wave = tid >> 6;    // 0..3
    const int lane = tid & 63;
    const int wt   = wave >> 1;   // 0..1 : t-half (64 rows)
    const int wd   = wave & 1;    // 0..1 : d-half (128 cols)
    const int l15  = lane & 15;
    const int l4   = lane >> 4;   // 0..3

    // A staging: thread -> row = tid>>1 (0..127), half = tid&1 (16 elems each)
    const int a_row  = tid >> 1;
    const int a_half = tid & 1;
    const int a_off  = a_row * LDK + a_half * 16;
    const float* qt  = q + ((size_t)(b * S_ + t0 + a_row)) * E2_ + a_half * 16;

    // B DMA: linear copy Wp step-image -> sB[h]; wave-uniform LDS base
    const char* wsrc = (const char*)Wp + wave * 5120 + lane * 16;
    const int   ldst = wave * 5120;

    float4 ra0, ra1, ra2, ra3;
    auto ALOAD = [&](int k0) {
        ra0 = *(const float4*)(qt + k0);
        ra1 = *(const float4*)(qt + k0 + 4);
        ra2 = *(const float4*)(qt + k0 + 8);
        ra3 = *(const float4*)(qt + k0 + 12);
    };
    auto AWRITE = [&](int k0, int h) {
        const float* qq = &sQs[k0 + a_half * 16];
        float4 q0 = *(const float4*)(qq);
        float4 q1 = *(const float4*)(qq + 4);
        float4 q2 = *(const float4*)(qq + 8);
        float4 q3 = *(const float4*)(qq + 12);
        f16x8 h0, h1;
        h0[0] = (_Float16)(ra0.x * q0.x); h0[1] = (_Float16)(ra0.y * q0.y);
        h0[2] = (_Float16)(ra0.z * q0.z); h0[3] = (_Float16)(ra0.w * q0.w);
        h0[4] = (_Float16)(ra1.x * q1.x); h0[5] = (_Float16)(ra1.y * q1.y);
        h0[6] = (_Float16)(ra1.z * q1.z); h0[7] = (_Float16)(ra1.w * q1.w);
        h1[0] = (_Float16)(ra2.x * q2.x); h1[1] = (_Float16)(ra2.y * q2.y);
        h1[2] = (_Float16)(ra2.z * q2.z); h1[3] = (_Float16)(ra2.w * q2.w);
        h1[4] = (_Float16)(ra3.x * q3.x); h1[5] = (_Float16)(ra3.y * q3.y);
        h1[6] = (_Float16)(ra3.z * q3.z); h1[7] = (_Float16)(ra3.w * q3.w);
        *(f16x8*)&sA[h][a_off]     = h0;
        *(f16x8*)&sA[h][a_off + 8] = h1;
    };
    auto BDMA = [&](int ko, int h) {
        const char* src = wsrc + ko * 20480;
        char* dst = (char*)&sB[h][0] + ldst;
#pragma unroll
        for (int j = 0; j < 5; ++j)
            gld16(src + j * 1024, dst + j * 1024);
    };

    f32x4 acc[4][8] = {};

    // prologue — order pinned so vmcnt counting is exact
    ALOAD(0);
    SBAR();
    AWRITE(0, 0);          // compiler inserts vmcnt wait for ra regs
    SBAR();
    BDMA(0, 0);            // 5 gld16 per wave
    SBAR();
    ALOAD(KB);             // 4 loads, must be issued LAST
    SBAR();
    asm volatile("s_waitcnt vmcnt(4) lgkmcnt(0)" ::: "memory");
    __builtin_amdgcn_s_barrier();

    for (int ko = 0; ko < E2_ / KB; ++ko) {
        const int h = ko & 1;
        f16x8 af[4], bf[8];
#pragma unroll
        for (int ft = 0; ft < 4; ++ft) {
            int row = wt * 64 + ft * 16 + l15;
            af[ft] = *(const f16x8*)&sA[h][row * LDK + l4 * 8];
        }
#pragma unroll
        for (int fd = 0; fd < 8; ++fd) {
            int row = wd * 128 + fd * 16 + l15;
            bf[fd] = *(const f16x8*)&sB[h][row * LDK + l4 * 8];
        }
        SBAR();
        if (ko < 15) {
            AWRITE((ko + 1) * KB, h ^ 1);   // uses ALOAD(ko+1) regs
            SBAR();
            BDMA(ko + 1, h ^ 1);            // 5 gld16
        }
        SBAR();
        if (ko < 14) {
            ALOAD((ko + 2) * KB);           // issued last -> the 4 left in flight
            SBAR();
            asm volatile("s_waitcnt vmcnt(4) lgkmcnt(0)" ::: "memory");
            __builtin_amdgcn_s_barrier();
        } else if (ko < 15) {
            asm volatile("s_waitcnt vmcnt(0) lgkmcnt(0)" ::: "memory");
            __builtin_amdgcn_s_barrier();
        }
        __builtin_amdgcn_s_setprio(1);
#pragma unroll
        for (int ft = 0; ft < 4; ++ft) {
#pragma unroll
            for (int fd = 0; fd < 8; ++fd) {
                acc[ft][fd] = __builtin_amdgcn_mfma_f32_16x16x32_f16(af[ft], bf[fd], acc[ft][fd], 0, 0, 0);
            }
        }
        __builtin_amdgcn_s_setprio(0);
    }

    __syncthreads();   // all frag reads done -> sA[0] reusable as sRed

    // ---- epilogue: tanh, *vd, reduce over d
    float* sRed = (float*)&sA[0][0];   // TT*2 floats
    {
        float vdr[8];
#pragma unroll
        for (int fd = 0; fd < 8; ++fd) vdr[fd] = sVd[wd * 128 + fd * 16 + l15];
#pragma unroll
        for (int ft = 0; ft < 4; ++ft) {
#pragma unroll
            for (int r = 0; r < 4; ++r) {
                float pp = 0.f;
#pragma unroll
                for (int fd = 0; fd < 8; ++fd)
                    pp += tanh_fast(acc[ft][fd][r]) * vdr[fd];
                pp += __shfl_xor(pp, 1);
                pp += __shfl_xor(pp, 2);
                pp += __shfl_xor(pp, 4);
                pp += __shfl_xor(pp, 8);
                if (l15 == 0) {
                    int tl = wt * 64 + ft * 16 + l4 * 4 + r;
                    sRed[tl * 2 + wd] = pp;
                }
            }
        }
    }
    __syncthreads();
    if (tid < TT) {
        float v = sRed[tid * 2 + 0] + sRed[tid * 2 + 1];
        int t = t0 + tid;
        logits[((size_t)(b * S_ + s)) * S_ + t] = v;   // direct
        logits[((size_t)(b * S_ + t)) * S_ + s] = v;   // mirror (bitwise-identical)
    }
}

// ---------------- softmax in place over rows of 512 ------------------------------
__global__ void softmax_k(float* __restrict__ atten) {
    const int row  = blockIdx.x;
    const int lane = threadIdx.x;
    float* p = atten + (size_t)row * S_;
    float4 v0 = *(float4*)(p + lane * 8);
    float4 v1 = *(float4*)(p + lane * 8 + 4);
    float vv[8] = {v0.x, v0.y, v0.z, v0.w, v1.x, v1.y, v1.z, v1.w};
    float m = vv[0];
#pragma unroll
    for (int j = 1; j < 8; ++j) m = fmaxf(m, vv[j]);
#pragma unroll
    for (int off = 1; off < 64; off <<= 1) m = fmaxf(m, __shfl_xor(m, off));
    float ssum = 0.f;
#pragma unroll
    for (int j = 0; j < 8; ++j) { vv[j] = __expf(vv[j] - m); ssum += vv[j]; }
#pragma unroll
    for (int off = 1; off < 64; off <<= 1) ssum += __shfl_xor(ssum, off);
    float inv = 1.0f / ssum;
    float4 o0 = {vv[0] * inv, vv[1] * inv, vv[2] * inv, vv[3] * inv};
    float4 o1 = {vv[4] * inv, vv[5] * inv, vv[6] * inv, vv[7] * inv};
    *(float4*)(p + lane * 8)     = o0;
    *(float4*)(p + lane * 8 + 4) = o1;
}

// ---------------- context = atten @ value (f32 tiled) -----------------------------
__global__ __launch_bounds__(256)
void context_k(const float* __restrict__ atten, const float* __restrict__ value,
               float* __restrict__ ctx) {
    __shared__ float sA[32][65];
    __shared__ float sV[64][65];
    const int b  = blockIdx.z;
    const int s0 = blockIdx.y * 32;
    const int e0 = blockIdx.x * 64;
    const int tid = threadIdx.x;
    const int ts = tid >> 4;
    const int te = tid & 15;

    float acc[2][4] = {};
    for (int k0 = 0; k0 < S_; k0 += 64) {
        {
            int r = tid >> 3;
            int c = (tid & 7) * 8;
            const float* ga = atten + ((size_t)(b * S_ + s0 + r)) * S_ + k0 + c;
            *(float4*)&sA[r][c]     = *(const float4*)ga;
            *(float4*)&sA[r][c + 4] = *(const float4*)(ga + 4);
        }
        {
            int r = tid >> 2;
            int c = (tid & 3) * 16;
            const float* gv = value + ((size_t)(b * S_ + k0 + r)) * E2_ + e0 + c;
#pragma unroll
            for (int j = 0; j < 16; j += 4)
                *(float4*)&sV[r][c + j] = *(const float4*)(gv + j);
        }
        __syncthreads();
#pragma unroll 8
        for (int kk = 0; kk < 64; ++kk) {
            float a0 = sA[ts * 2 + 0][kk];
            float a1 = sA[ts * 2 + 1][kk];
#pragma unroll
            for (int j = 0; j < 4; ++j) {
                float vvv = sV[kk][te * 4 + j];
                acc[0][j] += a0 * vvv;
                acc[1][j] += a1 * vvv;
            }
        }
        __syncthreads();
    }
#pragma unroll
    for (int i = 0; i < 2; ++i)
#pragma unroll
        for (int j = 0; j < 4; ++j)
            ctx[((size_t)(b * S_ + s0 + ts * 2 + i)) * E2_ + e0 + te * 4 + j] = acc[i][j];
}

extern "C" void kernel_launch(void* const* d_in, const int* in_sizes, int n_in,
                              void* d_out, int out_size, void* d_ws, size_t ws_size,
                              hipStream_t stream) {
    const float* query = (const float*)d_in[0];
    const float* value = (const float*)d_in[1];
    const float* Wd    = (const float*)d_in[2];
    const float* vd    = (const float*)d_in[3];

    float* out   = (float*)d_out;
    float* ctx   = out;                          // [B,S,E2]
    float* atten = out + (size_t)B_ * S_ * E2_;  // [B,S,S]

    // Wp padded step tiles: 16 * 256 * 40 * 2B = 320 KiB
    const size_t wdt_bytes = (size_t)16 * E_ * LDK * sizeof(_Float16);
    _Float16* wp;
    if (ws_size >= wdt_bytes) {
        wp = (_Float16*)d_ws;
    } else {
        wp = (_Float16*)ctx;   // overwritten later by context_k
    }

    prep_wdt<<<dim3(512), dim3(256), 0, stream>>>(Wd, wp);
    // dense triangular grid: 10 tile-pairs * 128 s-values = 1280 blocks per batch
    stage1<<<dim3(1280, B_), dim3(256), 0, stream>>>(query, wp, vd, atten);
    softmax_k<<<dim3(B_ * S_), dim3(64), 0, stream>>>(atten);
    context_k<<<dim3(E2_ / 64, S_ / 32, B_), dim3(256), 0, stream>>>(atten, value, ctx);
}

// Round 9
// 168.403 us; speedup vs baseline: 3.1522x; 1.0720x over previous
//
#include <hip/hip_runtime.h>

#define B_  2
#define S_  512
#define E2_ 512
#define E_  256

#define TT  128   // t-tile per block (stage1)
#define KB  32    // k-tile per step
#define LDK 40    // padded LDS row stride (f16 elems); pads never read

using f32x4 = __attribute__((ext_vector_type(4))) float;
using f16x8 = __attribute__((ext_vector_type(8))) _Float16;

__device__ __forceinline__ float tanh_fast(float x) {
    // NaN-safe: e->inf gives 1-0=1 ; e->0 gives 1-2=-1
    float e = __expf(2.0f * x);
    return 1.0f - 2.0f / (e + 1.0f);
}

__device__ __forceinline__ void gld16(const void* g, void* l) {
    __builtin_amdgcn_global_load_lds(
        (const __attribute__((address_space(1))) unsigned int*)g,
        (__attribute__((address_space(3))) unsigned int*)l, 16, 0, 0);
}

#define SBAR() __builtin_amdgcn_sched_barrier(0)

// ---- prep: Wd [E2][E] f32 -> Wp[ko][d][LDK] f16 step-tile images (padded) ------
__global__ void prep_wdt(const float* __restrict__ Wd, _Float16* __restrict__ Wp) {
    int idx = blockIdx.x * 256 + threadIdx.x;   // 0 .. 131071
    int h = idx >> 8;      // 0..511  (k index)
    int d = idx & 255;     // 0..255
    int ko = h >> 5;       // step
    int kk = h & 31;       // col within step
    Wp[(size_t)ko * (E_ * LDK) + d * LDK + kk] = (_Float16)Wd[idx];
}

// ---------------- stage1: logits[b,s,t], dense triangular grid -------------------
// blockIdx.x in [0,1280): p = x>>7 tile-pair (ti<=sj), sl = x&127 selects s
__global__ __launch_bounds__(512, 4)
void stage1(const float* __restrict__ q,
            const _Float16* __restrict__ Wp,
            const float* __restrict__ vd,
            float* __restrict__ logits /* [B*S, S] */) {
    const int p  = blockIdx.x >> 7;
    const int sl = blockIdx.x & 127;
    const int b  = blockIdx.y;
    const int sj = (p >= 6) ? 3 : (p >= 3) ? 2 : (p >= 1) ? 1 : 0;
    const int ti = p - ((sj * (sj + 1)) >> 1);
    const int s  = sj * TT + sl;
    const int t0 = ti * TT;

    __shared__ _Float16 sA[2][TT * LDK];   // 2 x 10 KiB
    __shared__ _Float16 sB[2][E_ * LDK];   // 2 x 20 KiB
    __shared__ float sQs[E2_];             // 2 KiB
    __shared__ float sVd[E_];              // 1 KiB

    const int tid = threadIdx.x;   // 0..511
    {
        const float* qsrow = q + ((size_t)(b * S_ + s)) * E2_;
        sQs[tid] = qsrow[tid];
        if (tid < E_) sVd[tid] = vd[tid];
    }
    __syncthreads();

    const int wave = tid >> 6;    // 0..7
    const int lane = tid & 63;
    const int wt   = wave >> 2;   // 0..1 : t-half (64 rows)
    const int wd   = wave & 3;    // 0..3 : d-quarter (64 cols)
    const int l15  = lane & 15;
    const int l4   = lane >> 4;   // 0..3

    // A staging: thread -> row = tid>>2 (0..127), granule = tid&3 (8 f32 each)
    const int a_row = tid >> 2;
    const int a_g   = tid & 3;
    const int a_off = a_row * LDK + a_g * 8;
    const float* qt = q + ((size_t)(b * S_ + t0 + a_row)) * E2_ + a_g * 8;

    // B DMA: linear copy Wp step-image (20480 B) -> sB[h]; wave-uniform LDS base.
    // 8 waves x 1024 B x 2 rounds = 16384 B; waves 0-3 do a 3rd round = +4096 B.
    const char* wsrc = (const char*)Wp + wave * 1024 + lane * 16;
    const int   ldst = wave * 1024;

    float4 ra0, ra1;
    auto ALOAD = [&](int k0) {
        ra0 = *(const float4*)(qt + k0);
        ra1 = *(const float4*)(qt + k0 + 4);
    };
    auto AWRITE = [&](int k0, int h) {
        const float* qq = &sQs[k0 + a_g * 8];
        float4 q0 = *(const float4*)(qq);
        float4 q1 = *(const float4*)(qq + 4);
        f16x8 hv;
        hv[0] = (_Float16)(ra0.x * q0.x); hv[1] = (_Float16)(ra0.y * q0.y);
        hv[2] = (_Float16)(ra0.z * q0.z); hv[3] = (_Float16)(ra0.w * q0.w);
        hv[4] = (_Float16)(ra1.x * q1.x); hv[5] = (_Float16)(ra1.y * q1.y);
        hv[6] = (_Float16)(ra1.z * q1.z); hv[7] = (_Float16)(ra1.w * q1.w);
        *(f16x8*)&sA[h][a_off] = hv;
    };
    auto BDMA = [&](int ko, int h) {
        const char* src = wsrc + ko * 20480;
        char* dst = (char*)&sB[h][0] + ldst;
        gld16(src,        dst);
        gld16(src + 8192, dst + 8192);
        if (wave < 4) gld16(src + 16384, dst + 16384);
    };

    f32x4 acc[4][4] = {};

    // prologue — order pinned so vmcnt counting is exact
    ALOAD(0);
    SBAR();
    AWRITE(0, 0);          // compiler inserts vmcnt wait for ra regs
    SBAR();
    BDMA(0, 0);            // 2-3 gld16 per wave
    SBAR();
    ALOAD(KB);             // 2 loads, issued LAST
    SBAR();
    asm volatile("s_waitcnt vmcnt(2) lgkmcnt(0)" ::: "memory");
    __builtin_amdgcn_s_barrier();

    for (int ko = 0; ko < E2_ / KB; ++ko) {
        const int h = ko & 1;
        f16x8 af[4], bf[4];
#pragma unroll
        for (int ft = 0; ft < 4; ++ft) {
            int row = wt * 64 + ft * 16 + l15;
            af[ft] = *(const f16x8*)&sA[h][row * LDK + l4 * 8];
        }
#pragma unroll
        for (int fd = 0; fd < 4; ++fd) {
            int row = wd * 64 + fd * 16 + l15;
            bf[fd] = *(const f16x8*)&sB[h][row * LDK + l4 * 8];
        }
        SBAR();
        if (ko < 15) {
            AWRITE((ko + 1) * KB, h ^ 1);   // uses ALOAD(ko+1) regs
            SBAR();
            BDMA(ko + 1, h ^ 1);            // 2-3 gld16
        }
        SBAR();
        if (ko < 14) {
            ALOAD((ko + 2) * KB);           // issued last -> the 2 left in flight
            SBAR();
            asm volatile("s_waitcnt vmcnt(2) lgkmcnt(0)" ::: "memory");
            __builtin_amdgcn_s_barrier();
        } else if (ko < 15) {
            asm volatile("s_waitcnt vmcnt(0) lgkmcnt(0)" ::: "memory");
            __builtin_amdgcn_s_barrier();
        }
        __builtin_amdgcn_s_setprio(1);
#pragma unroll
        for (int ft = 0; ft < 4; ++ft) {
#pragma unroll
            for (int fd = 0; fd < 4; ++fd) {
                acc[ft][fd] = __builtin_amdgcn_mfma_f32_16x16x32_f16(af[ft], bf[fd], acc[ft][fd], 0, 0, 0);
            }
        }
        __builtin_amdgcn_s_setprio(0);
    }

    __syncthreads();   // all frag reads done -> sA[0] reusable as sRed

    // ---- epilogue: tanh, *vd, reduce over d
    float* sRed = (float*)&sA[0][0];   // TT*4 floats
    {
        float vdr[4];
#pragma unroll
        for (int fd = 0; fd < 4; ++fd) vdr[fd] = sVd[wd * 64 + fd * 16 + l15];
#pragma unroll
        for (int ft = 0; ft < 4; ++ft) {
#pragma unroll
            for (int r = 0; r < 4; ++r) {
                float pp = 0.f;
#pragma unroll
                for (int fd = 0; fd < 4; ++fd)
                    pp += tanh_fast(acc[ft][fd][r]) * vdr[fd];
                pp += __shfl_xor(pp, 1);
                pp += __shfl_xor(pp, 2);
                pp += __shfl_xor(pp, 4);
                pp += __shfl_xor(pp, 8);
                if (l15 == 0) {
                    int tl = wt * 64 + ft * 16 + l4 * 4 + r;
                    sRed[tl * 4 + wd] = pp;
                }
            }
        }
    }
    __syncthreads();
    if (tid < TT) {
        float v = sRed[tid * 4 + 0] + sRed[tid * 4 + 1] + sRed[tid * 4 + 2] + sRed[tid * 4 + 3];
        int t = t0 + tid;
        logits[((size_t)(b * S_ + s)) * S_ + t] = v;   // direct
        logits[((size_t)(b * S_ + t)) * S_ + s] = v;   // mirror (bitwise-identical)
    }
}

// ---------------- softmax in place over rows of 512 ------------------------------
__global__ void softmax_k(float* __restrict__ atten) {
    const int row  = blockIdx.x;
    const int lane = threadIdx.x;
    float* p = atten + (size_t)row * S_;
    float4 v0 = *(float4*)(p + lane * 8);
    float4 v1 = *(float4*)(p + lane * 8 + 4);
    float vv[8] = {v0.x, v0.y, v0.z, v0.w, v1.x, v1.y, v1.z, v1.w};
    float m = vv[0];
#pragma unroll
    for (int j = 1; j < 8; ++j) m = fmaxf(m, vv[j]);
#pragma unroll
    for (int off = 1; off < 64; off <<= 1) m = fmaxf(m, __shfl_xor(m, off));
    float ssum = 0.f;
#pragma unroll
    for (int j = 0; j < 8; ++j) { vv[j] = __expf(vv[j] - m); ssum += vv[j]; }
#pragma unroll
    for (int off = 1; off < 64; off <<= 1) ssum += __shfl_xor(ssum, off);
    float inv = 1.0f / ssum;
    float4 o0 = {vv[0] * inv, vv[1] * inv, vv[2] * inv, vv[3] * inv};
    float4 o1 = {vv[4] * inv, vv[5] * inv, vv[6] * inv, vv[7] * inv};
    *(float4*)(p + lane * 8)     = o0;
    *(float4*)(p + lane * 8 + 4) = o1;
}

// ---------------- context = atten @ value (f32 tiled) -----------------------------
__global__ __launch_bounds__(256)
void context_k(const float* __restrict__ atten, const float* __restrict__ value,
               float* __restrict__ ctx) {
    __shared__ float sA[32][65];
    __shared__ float sV[64][65];
    const int b  = blockIdx.z;
    const int s0 = blockIdx.y * 32;
    const int e0 = blockIdx.x * 64;
    const int tid = threadIdx.x;
    const int ts = tid >> 4;
    const int te = tid & 15;

    float acc[2][4] = {};
    for (int k0 = 0; k0 < S_; k0 += 64) {
        {
            int r = tid >> 3;
            int c = (tid & 7) * 8;
            const float* ga = atten + ((size_t)(b * S_ + s0 + r)) * S_ + k0 + c;
            *(float4*)&sA[r][c]     = *(const float4*)ga;
            *(float4*)&sA[r][c + 4] = *(const float4*)(ga + 4);
        }
        {
            int r = tid >> 2;
            int c = (tid & 3) * 16;
            const float* gv = value + ((size_t)(b * S_ + k0 + r)) * E2_ + e0 + c;
#pragma unroll
            for (int j = 0; j < 16; j += 4)
                *(float4*)&sV[r][c + j] = *(const float4*)(gv + j);
        }
        __syncthreads();
#pragma unroll 8
        for (int kk = 0; kk < 64; ++kk) {
            float a0 = sA[ts * 2 + 0][kk];
            float a1 = sA[ts * 2 + 1][kk];
#pragma unroll
            for (int j = 0; j < 4; ++j) {
                float vvv = sV[kk][te * 4 + j];
                acc[0][j] += a0 * vvv;
                acc[1][j] += a1 * vvv;
            }
        }
        __syncthreads();
    }
#pragma unroll
    for (int i = 0; i < 2; ++i)
#pragma unroll
        for (int j = 0; j < 4; ++j)
            ctx[((size_t)(b * S_ + s0 + ts * 2 + i)) * E2_ + e0 + te * 4 + j] = acc[i][j];
}

extern "C" void kernel_launch(void* const* d_in, const int* in_sizes, int n_in,
                              void* d_out, int out_size, void* d_ws, size_t ws_size,
                              hipStream_t stream) {
    const float* query = (const float*)d_in[0];
    const float* value = (const float*)d_in[1];
    const float* Wd    = (const float*)d_in[2];
    const float* vd    = (const float*)d_in[3];

    float* out   = (float*)d_out;
    float* ctx   = out;                          // [B,S,E2]
    float* atten = out + (size_t)B_ * S_ * E2_;  // [B,S,S]

    // Wp padded step tiles: 16 * 256 * 40 * 2B = 320 KiB
    const size_t wdt_bytes = (size_t)16 * E_ * LDK * sizeof(_Float16);
    _Float16* wp;
    if (ws_size >= wdt_bytes) {
        wp = (_Float16*)d_ws;
    } else {
        wp = (_Float16*)ctx;   // overwritten later by context_k
    }

    prep_wdt<<<dim3(512), dim3(256), 0, stream>>>(Wd, wp);
    // dense triangular grid: 10 tile-pairs * 128 s-values = 1280 blocks per batch
    stage1<<<dim3(1280, B_), dim3(512), 0, stream>>>(query, wp, vd, atten);
    softmax_k<<<dim3(B_ * S_), dim3(64), 0, stream>>>(atten);
    context_k<<<dim3(E2_ / 64, S_ / 32, B_), dim3(256), 0, stream>>>(atten, value, ctx);
}

// Round 10
// 160.121 us; speedup vs baseline: 3.3153x; 1.0517x over previous
//
#include <hip/hip_runtime.h>

#define B_  2
#define S_  512
#define E2_ 512
#define E_  256

#define TT  128   // t-tile per block (stage1)
#define KB  32    // k-tile per step
#define LDK 40    // padded LDS row stride for sA (80 B, 16B-aligned, bank-clean)

using f32x4 = __attribute__((ext_vector_type(4))) float;
using f16x8 = __attribute__((ext_vector_type(8))) _Float16;

__device__ __forceinline__ float tanh_fast(float x) {
    // NaN-safe: e->inf gives 1-0=1 ; e->0 gives 1-2=-1
    float e = __expf(2.0f * x);
    return 1.0f - 2.0f / (e + 1.0f);
}

#define SBAR() __builtin_amdgcn_sched_barrier(0)

// ---- prep: Wd [E2][E] f32 -> Wp2[ko][d][kk] compact f16 step tiles -------------
__global__ void prep_wdt(const float* __restrict__ Wd, _Float16* __restrict__ Wp2) {
    int idx = blockIdx.x * 256 + threadIdx.x;   // 0 .. 131071
    int h = idx >> 8;      // 0..511  (k index)
    int d = idx & 255;     // 0..255
    int ko = h >> 5;       // step
    int kk = h & 31;       // col within step
    Wp2[ko * (E_ * KB) + d * KB + kk] = (_Float16)Wd[idx];
}

// ---------------- stage1: logits[b,s,t], dense triangular grid -------------------
// blockIdx.x in [0,1280): p = x>>7 tile-pair (ti<=sj), sl = x&127 selects s
__global__ __launch_bounds__(512, 4)
void stage1(const float* __restrict__ q,
            const _Float16* __restrict__ Wp2,
            const float* __restrict__ vd,
            float* __restrict__ logits /* [B*S, S] */) {
    const int p  = blockIdx.x >> 7;
    const int sl = blockIdx.x & 127;
    const int b  = blockIdx.y;
    const int sj = (p >= 6) ? 3 : (p >= 3) ? 2 : (p >= 1) ? 1 : 0;
    const int ti = p - ((sj * (sj + 1)) >> 1);
    const int s  = sj * TT + sl;
    const int t0 = ti * TT;

    __shared__ _Float16 sA[2][TT * LDK];   // 2 x 10 KiB
    __shared__ float sQs[E2_];             // 2 KiB
    __shared__ float sVd[E_];              // 1 KiB

    const int tid = threadIdx.x;   // 0..511
    {
        const float* qsrow = q + ((size_t)(b * S_ + s)) * E2_;
        sQs[tid] = qsrow[tid];
        if (tid < E_) sVd[tid] = vd[tid];
    }
    __syncthreads();

    const int wave = tid >> 6;    // 0..7
    const int lane = tid & 63;
    const int wt   = wave >> 2;   // 0..1 : t-half (64 rows)
    const int wd   = wave & 3;    // 0..3 : d-quarter (64 cols)
    const int l15  = lane & 15;
    const int l4   = lane >> 4;   // 0..3

    // A staging: thread -> row = tid>>2 (0..127), granule = tid&3 (8 f32 each)
    const int a_row = tid >> 2;
    const int a_g   = tid & 3;
    const int a_off = a_row * LDK + a_g * 8;
    const float* qt = q + ((size_t)(b * S_ + t0 + a_row)) * E2_ + a_g * 8;

    // B fragments: direct global->reg from compact Wp2 (L2-resident)
    const _Float16* wpb = Wp2 + (wd * 64 + l15) * KB + l4 * 8;   // + fd*16*KB + ko*E_*KB

    float4 ra0, ra1;
    auto ALOAD = [&](int k0) {
        ra0 = *(const float4*)(qt + k0);
        ra1 = *(const float4*)(qt + k0 + 4);
    };
    auto AWRITE = [&](int k0, int h) {
        const float* qq = &sQs[k0 + a_g * 8];
        float4 q0 = *(const float4*)(qq);
        float4 q1 = *(const float4*)(qq + 4);
        f16x8 hv;
        hv[0] = (_Float16)(ra0.x * q0.x); hv[1] = (_Float16)(ra0.y * q0.y);
        hv[2] = (_Float16)(ra0.z * q0.z); hv[3] = (_Float16)(ra0.w * q0.w);
        hv[4] = (_Float16)(ra1.x * q1.x); hv[5] = (_Float16)(ra1.y * q1.y);
        hv[6] = (_Float16)(ra1.z * q1.z); hv[7] = (_Float16)(ra1.w * q1.w);
        *(f16x8*)&sA[h][a_off] = hv;
    };

    f32x4 acc[4][4] = {};

    // prologue
    ALOAD(0);
    SBAR();
    AWRITE(0, 0);          // compiler inserts exact vmcnt wait for ra regs
    SBAR();
    ALOAD(KB);             // stays in flight across the barrier
    SBAR();
    asm volatile("s_waitcnt lgkmcnt(0)" ::: "memory");
    __builtin_amdgcn_s_barrier();
    SBAR();

    for (int ko = 0; ko < E2_ / KB; ++ko) {
        const int h = ko & 1;
        // B frags for THIS step: 4 global b128 loads, latency covered below
        f16x8 bf[4];
        {
            const _Float16* wk = wpb + ko * (E_ * KB);
#pragma unroll
            for (int fd = 0; fd < 4; ++fd)
                bf[fd] = *(const f16x8*)(wk + fd * 16 * KB);
        }
        SBAR();
        f16x8 af[4];
#pragma unroll
        for (int ft = 0; ft < 4; ++ft) {
            int row = wt * 64 + ft * 16 + l15;
            af[ft] = *(const f16x8*)&sA[h][row * LDK + l4 * 8];
        }
        SBAR();
        if (ko < 15) {
            AWRITE((ko + 1) * KB, h ^ 1);   // uses ra from previous step
            SBAR();
        }
        if (ko < 14) {
            ALOAD((ko + 2) * KB);           // reg-dest, spans the barrier
            SBAR();
        }
        if (ko < 15) {
            asm volatile("s_waitcnt lgkmcnt(0)" ::: "memory");  // LDS ops only
            __builtin_amdgcn_s_barrier();
            SBAR();
        }
        __builtin_amdgcn_s_setprio(1);
#pragma unroll
        for (int ft = 0; ft < 4; ++ft) {
#pragma unroll
            for (int fd = 0; fd < 4; ++fd) {
                acc[ft][fd] = __builtin_amdgcn_mfma_f32_16x16x32_f16(af[ft], bf[fd], acc[ft][fd], 0, 0, 0);
            }
        }
        __builtin_amdgcn_s_setprio(0);
    }

    __syncthreads();   // all frag reads done -> sA reusable as sRed

    // ---- epilogue: tanh, *vd, reduce over d
    float* sRed = (float*)&sA[0][0];   // TT*4 floats
    {
        float vdr[4];
#pragma unroll
        for (int fd = 0; fd < 4; ++fd) vdr[fd] = sVd[wd * 64 + fd * 16 + l15];
#pragma unroll
        for (int ft = 0; ft < 4; ++ft) {
#pragma unroll
            for (int r = 0; r < 4; ++r) {
                float pp = 0.f;
#pragma unroll
                for (int fd = 0; fd < 4; ++fd)
                    pp += tanh_fast(acc[ft][fd][r]) * vdr[fd];
                pp += __shfl_xor(pp, 1);
                pp += __shfl_xor(pp, 2);
                pp += __shfl_xor(pp, 4);
                pp += __shfl_xor(pp, 8);
                if (l15 == 0) {
                    int tl = wt * 64 + ft * 16 + l4 * 4 + r;
                    sRed[tl * 4 + wd] = pp;
                }
            }
        }
    }
    __syncthreads();
    if (tid < TT) {
        float v = sRed[tid * 4 + 0] + sRed[tid * 4 + 1] + sRed[tid * 4 + 2] + sRed[tid * 4 + 3];
        int t = t0 + tid;
        logits[((size_t)(b * S_ + s)) * S_ + t] = v;   // direct
        logits[((size_t)(b * S_ + t)) * S_ + s] = v;   // mirror (bitwise-identical)
    }
}

// ---------------- softmax in place over rows of 512 ------------------------------
__global__ void softmax_k(float* __restrict__ atten) {
    const int row  = blockIdx.x;
    const int lane = threadIdx.x;
    float* p = atten + (size_t)row * S_;
    float4 v0 = *(float4*)(p + lane * 8);
    float4 v1 = *(float4*)(p + lane * 8 + 4);
    float vv[8] = {v0.x, v0.y, v0.z, v0.w, v1.x, v1.y, v1.z, v1.w};
    float m = vv[0];
#pragma unroll
    for (int j = 1; j < 8; ++j) m = fmaxf(m, vv[j]);
#pragma unroll
    for (int off = 1; off < 64; off <<= 1) m = fmaxf(m, __shfl_xor(m, off));
    float ssum = 0.f;
#pragma unroll
    for (int j = 0; j < 8; ++j) { vv[j] = __expf(vv[j] - m); ssum += vv[j]; }
#pragma unroll
    for (int off = 1; off < 64; off <<= 1) ssum += __shfl_xor(ssum, off);
    float inv = 1.0f / ssum;
    float4 o0 = {vv[0] * inv, vv[1] * inv, vv[2] * inv, vv[3] * inv};
    float4 o1 = {vv[4] * inv, vv[5] * inv, vv[6] * inv, vv[7] * inv};
    *(float4*)(p + lane * 8)     = o0;
    *(float4*)(p + lane * 8 + 4) = o1;
}

// ---------------- context = atten @ value (f32 tiled) -----------------------------
__global__ __launch_bounds__(256)
void context_k(const float* __restrict__ atten, const float* __restrict__ value,
               float* __restrict__ ctx) {
    __shared__ float sA[32][65];
    __shared__ float sV[64][65];
    const int b  = blockIdx.z;
    const int s0 = blockIdx.y * 32;
    const int e0 = blockIdx.x * 64;
    const int tid = threadIdx.x;
    const int ts = tid >> 4;
    const int te = tid & 15;

    float acc[2][4] = {};
    for (int k0 = 0; k0 < S_; k0 += 64) {
        {
            int r = tid >> 3;
            int c = (tid & 7) * 8;
            const float* ga = atten + ((size_t)(b * S_ + s0 + r)) * S_ + k0 + c;
            *(float4*)&sA[r][c]     = *(const float4*)ga;
            *(float4*)&sA[r][c + 4] = *(const float4*)(ga + 4);
        }
        {
            int r = tid >> 2;
            int c = (tid & 3) * 16;
            const float* gv = value + ((size_t)(b * S_ + k0 + r)) * E2_ + e0 + c;
#pragma unroll
            for (int j = 0; j < 16; j += 4)
                *(float4*)&sV[r][c + j] = *(const float4*)(gv + j);
        }
        __syncthreads();
#pragma unroll 8
        for (int kk = 0; kk < 64; ++kk) {
            float a0 = sA[ts * 2 + 0][kk];
            float a1 = sA[ts * 2 + 1][kk];
#pragma unroll
            for (int j = 0; j < 4; ++j) {
                float vvv = sV[kk][te * 4 + j];
                acc[0][j] += a0 * vvv;
                acc[1][j] += a1 * vvv;
            }
        }
        __syncthreads();
    }
#pragma unroll
    for (int i = 0; i < 2; ++i)
#pragma unroll
        for (int j = 0; j < 4; ++j)
            ctx[((size_t)(b * S_ + s0 + ts * 2 + i)) * E2_ + e0 + te * 4 + j] = acc[i][j];
}

extern "C" void kernel_launch(void* const* d_in, const int* in_sizes, int n_in,
                              void* d_out, int out_size, void* d_ws, size_t ws_size,
                              hipStream_t stream) {
    const float* query = (const float*)d_in[0];
    const float* value = (const float*)d_in[1];
    const float* Wd    = (const float*)d_in[2];
    const float* vd    = (const float*)d_in[3];

    float* out   = (float*)d_out;
    float* ctx   = out;                          // [B,S,E2]
    float* atten = out + (size_t)B_ * S_ * E2_;  // [B,S,S]

    // Wp2 compact step tiles: 16 * 256 * 32 * 2B = 256 KiB
    const size_t wdt_bytes = (size_t)16 * E_ * KB * sizeof(_Float16);
    _Float16* wp2;
    if (ws_size >= wdt_bytes) {
        wp2 = (_Float16*)d_ws;
    } else {
        wp2 = (_Float16*)ctx;   // overwritten later by context_k
    }

    prep_wdt<<<dim3(512), dim3(256), 0, stream>>>(Wd, wp2);
    // dense triangular grid: 10 tile-pairs * 128 s-values = 1280 blocks per batch
    stage1<<<dim3(1280, B_), dim3(512), 0, stream>>>(query, wp2, vd, atten);
    softmax_k<<<dim3(B_ * S_), dim3(64), 0, stream>>>(atten);
    context_k<<<dim3(E2_ / 64, S_ / 32, B_), dim3(256), 0, stream>>>(atten, value, ctx);
}